// Round 12
// baseline (177.173 us; speedup 1.0000x reference)
//
#include <hip/hip_runtime.h>

// ---------------------------------------------------------------------------
// QuaternionLinear == one dense GEMM: out[M,N] = x[M,K] @ W_eff[N,K]^T + bias
//   M = 16384 (B*S), N = 2048 (OUT_F), K = 2048 (IN_F)
// Pipeline: prep (fp32->bf16 x + build W_eff) ; qgemm.
// R12: CROSS-TILE OPERAND PRE-READ. R5-R7 landed at ~4650cyc/tile ~= the SUM
// of the MFMA pipe (2483) and LDS pipe (2560) because each cluster's MFMA
// waits on reads issued in the same cluster. Now every cluster's operands
// are read one cluster ahead; the tile-boundary cluster (c0) uses frags
// pre-read at c3 of the previous tile. Rings: A x3 + B x2 = 160KB exactly.
//   per tile t: c0{stage B(t+1)h0; read aN;      mfma acc[0..3]+=aC*bC}
//               c1{stage B(t+1)h1; read aM,bN;   mfma acc[4..7]+=aN*bC}
//               c2{stage A(t+2)h0; read aP;      mfma acc[0..3]+=aM*bN}
//               MID: vmcnt(2)+barrier  (B(t+1),A(t+1) landed, all waves)
//               c3{stage A(t+2)h1; PRE-READ aC,bC from A(t+1)%3,B(t+1)&1;
//                                               mfma acc[4..7]+=aP*bN}
//               END: vmcnt(4)+barrier  (in-flight = A(t+2)x4 only)
// Safety: A-buf (t+1)%3 written t-1, next written t+2; B-buf (t+1)&1 fully
// written before MID barrier, next written t+2; every tile-t read is MFMA-
// consumed before the barrier preceding its next writer. R11 lesson: keep
// the verified 16x16 frag pattern (32-row 32x32 reads = unavoidable 4-way
// bank conflict). R9 lesson: no divergence around acc.
// ---------------------------------------------------------------------------

typedef unsigned short u16;
typedef __bf16 bf16x8 __attribute__((ext_vector_type(8)));
typedef float f32x4 __attribute__((ext_vector_type(4)));

#define QM 16384
#define QN 2048
#define QK 2048

__device__ __forceinline__ u16 f2bf(float f) {
    union { float f; unsigned u; } v;
    v.f = f;
    unsigned r = v.u + 0x7FFFu + ((v.u >> 16) & 1u);
    return (u16)(r >> 16);
}

__device__ __forceinline__ void async_copy16(const u16* g, u16* l) {
    __builtin_amdgcn_global_load_lds(
        (const __attribute__((address_space(1))) void*)g,
        (__attribute__((address_space(3))) void*)l,
        16, 0, 0);
}

// ---------------------------------------------------------------------------
// prep: blocks [0,4096) convert x fp32->bf16; blocks [4096,8192) build W_eff.
// ---------------------------------------------------------------------------
__global__ void prep_kernel(const float* __restrict__ x, u16* __restrict__ xb,
                            const float* __restrict__ wr, const float* __restrict__ wi,
                            const float* __restrict__ wj, const float* __restrict__ wk,
                            u16* __restrict__ wb) {
    const int b = blockIdx.x;
    if (b < 4096) {
        const int n4 = (QM * QK) / 4;
        for (int i = b * blockDim.x + threadIdx.x; i < n4; i += 4096 * blockDim.x) {
            float4 v = reinterpret_cast<const float4*>(x)[i];
            ushort4 o;
            o.x = f2bf(v.x); o.y = f2bf(v.y); o.z = f2bf(v.z); o.w = f2bf(v.w);
            reinterpret_cast<ushort4*>(xb)[i] = o;
        }
    } else {
        int i = (b - 4096) * blockDim.x + threadIdx.x;   // [0, QN*QK/4)
        int n = i >> 9;
        int p = i & 511;
        int q = n >> 2, co = n & 3;
        int base = (q << 9) + p;
        float r  = wr[base], ii = wi[base], jj = wj[base], kk = wk[base];
        float e0, e1, e2, e3;
        if      (co == 0) { e0 = r;  e1 = -ii; e2 = -jj; e3 = -kk; }
        else if (co == 1) { e0 = ii; e1 = r;   e2 = -jj; e3 = kk;  }
        else if (co == 2) { e0 = jj; e1 = ii;  e2 = r;   e3 = -kk; }
        else              { e0 = kk; e1 = -ii; e2 = jj;  e3 = r;   }
        ushort4 o;
        o.x = f2bf(e0); o.y = f2bf(e1); o.z = f2bf(e2); o.w = f2bf(e3);
        reinterpret_cast<ushort4*>(wb)[(n << 9) + p] = o;
    }
}

// ---------------------------------------------------------------------------
// LDS (u16): A bufs [0,49152) = 3 x 16384; B bufs [49152,81920) = 2 x 16384.
// Buf = 256 rows x 64 cols; physical 16B-chunk (r,cp) holds logical
// (r, cp ^ (r&7)) [involution, verified 0-conflict 16x16 read pattern].
// vmcnt ledger (loads; stage() = 2 loads): start of t: [A(t+1)x4];
//   +B(t+1)x4 (c0,c1) +A(t+2)x2 (c2) -> MID vmcnt(2); +A(t+2)x2 (c3)
//   -> END vmcnt(4) => invariant holds.
// ---------------------------------------------------------------------------
__global__ __launch_bounds__(512, 2) void qgemm_kernel(const u16* __restrict__ A,
                                                       const u16* __restrict__ B,
                                                       const float* __restrict__ bias,
                                                       float* __restrict__ C) {
    __shared__ __align__(16) u16 L[81920];      // 160 KB

    const int bid = blockIdx.x;                 // 512 blocks, %8==0
    const int swz = (bid & 7) * 64 + (bid >> 3);
    const int bm = swz >> 3;                    // 0..63
    const int bn = swz & 7;                     // 0..7

    const int tid = threadIdx.x;
    const int wid = tid >> 6, lane = tid & 63;
    const int wm = wid >> 2, wn = wid & 3;
    const int lr = lane & 15, lg = lane >> 4;

    const u16* Asrc = A + (size_t)bm * 256 * QK;
    const u16* Bsrc = B + (size_t)bn * 256 * QK;

    // staging: half-tile = 128 rows x 64 cols; thread covers rows {rA, rA+64}
    const int rA  = tid >> 3;                        // 0..63
    const int clA = ((tid & 7) ^ (rA & 7)) << 3;     // pre-swizzled global col
    const size_t soff = (size_t)rA * QK + clA;

    f32x4 acc[8][4];
#pragma unroll
    for (int i = 0; i < 8; ++i)
#pragma unroll
        for (int j = 0; j < 4; ++j)
            acc[i][j] = (f32x4){0.f, 0.f, 0.f, 0.f};

    auto stage = [&](const u16* src, int lbase, int k0) {
#pragma unroll
        for (int o = 0; o < 2; ++o)
            async_copy16(src + (size_t)(o * 64) * QK + k0 + soff,
                         &L[lbase + o * 4096 + wid * 512]);
    };

    auto rdA = [&](const u16* LA, int mf, int ks) -> bf16x8 {
        const int r = wm * 128 + mf * 16 + lr;
        const int c = ((ks * 4 + lg) ^ (r & 7)) << 3;
        return *(const bf16x8*)&LA[r * 64 + c];
    };
    auto rdB = [&](const u16* LB, int nf, int ks) -> bf16x8 {
        const int r = wn * 64 + nf * 16 + lr;
        const int c = ((ks * 4 + lg) ^ (r & 7)) << 3;
        return *(const bf16x8*)&LB[r * 64 + c];
    };

    // carried across tiles: next tile's cluster-0 operands
    bf16x8 aC[4], bC[4];

    // cA=t%3, nA=(t+1)%3, sA=(t+2)%3, cB=t&1 — all LITERAL at call sites.
    auto doTile = [&](const int cA, const int nA, const int sA, const int cB,
                      const int t) __attribute__((always_inline)) {
        const u16* LA  = &L[cA * 16384];
        const u16* LB  = &L[49152 + cB * 16384];
        const u16* LAn = &L[nA * 16384];
        const u16* LBn = &L[49152 + (cB ^ 1) * 16384];
        const int oB = 49152 + (cB ^ 1) * 16384;   // B(t+1) dest
        const int oA = sA * 16384;                 // A(t+2) dest
        const int tw1 = (t + 1) & 31, tw2 = (t + 2) & 31;

        bf16x8 aN[4], aM[4], bN[4], aP[4];

        // ---- c0 (ks0, mh0): operands pre-read last tile -----------------
#pragma unroll
        for (int mf = 0; mf < 4; ++mf) aN[mf] = rdA(LA, 4 + mf, 0);
        stage(Bsrc, oB, tw1 * 64);
#pragma unroll
        for (int mf = 0; mf < 4; ++mf)
#pragma unroll
            for (int nf = 0; nf < 4; ++nf)
                acc[mf][nf] = __builtin_amdgcn_mfma_f32_16x16x32_bf16(aC[mf], bC[nf], acc[mf][nf], 0, 0, 0);

        // ---- c1 (ks0, mh1) ----------------------------------------------
#pragma unroll
        for (int mf = 0; mf < 4; ++mf) aM[mf] = rdA(LA, mf, 1);
#pragma unroll
        for (int nf = 0; nf < 4; ++nf) bN[nf] = rdB(LB, nf, 1);
        stage(Bsrc + 128 * QK, oB + 8192, tw1 * 64);
#pragma unroll
        for (int mf = 0; mf < 4; ++mf)
#pragma unroll
            for (int nf = 0; nf < 4; ++nf)
                acc[4 + mf][nf] = __builtin_amdgcn_mfma_f32_16x16x32_bf16(aN[mf], bC[nf], acc[4 + mf][nf], 0, 0, 0);

        // ---- c2 (ks1, mh0) ----------------------------------------------
#pragma unroll
        for (int mf = 0; mf < 4; ++mf) aP[mf] = rdA(LA, 4 + mf, 1);
        stage(Asrc, oA, tw2 * 64);
#pragma unroll
        for (int mf = 0; mf < 4; ++mf)
#pragma unroll
            for (int nf = 0; nf < 4; ++nf)
                acc[mf][nf] = __builtin_amdgcn_mfma_f32_16x16x32_bf16(aM[mf], bN[nf], acc[mf][nf], 0, 0, 0);

        // ---- MID sync: A(t+1)+B(t+1) landed for ALL waves ----------------
        asm volatile("s_waitcnt vmcnt(2)" ::: "memory");
        __builtin_amdgcn_s_barrier();

        // ---- c3 (ks1, mh1): pre-read next tile's c0 operands -------------
#pragma unroll
        for (int mf = 0; mf < 4; ++mf) aC[mf] = rdA(LAn, mf, 0);
#pragma unroll
        for (int nf = 0; nf < 4; ++nf) bC[nf] = rdB(LBn, nf, 0);
        stage(Asrc + 128 * QK, oA + 8192, tw2 * 64);
#pragma unroll
        for (int mf = 0; mf < 4; ++mf)
#pragma unroll
            for (int nf = 0; nf < 4; ++nf)
                acc[4 + mf][nf] = __builtin_amdgcn_mfma_f32_16x16x32_bf16(aP[mf], bN[nf], acc[4 + mf][nf], 0, 0, 0);

        // ---- END sync: in-flight = A(t+2) x4 only ------------------------
        asm volatile("s_waitcnt vmcnt(4)" ::: "memory");
        __builtin_amdgcn_s_barrier();
    };

    // prologue: A(0)->A0, B(0)->B0, A(1)->A1 (B(1) is staged by tile 0)
    stage(Asrc,            0,             0);
    stage(Asrc + 128 * QK, 8192,          0);
    stage(Bsrc,            49152,             0);
    stage(Bsrc + 128 * QK, 49152 + 8192,      0);
    stage(Asrc,            16384,            64);
    stage(Asrc + 128 * QK, 16384 + 8192,     64);
    asm volatile("s_waitcnt vmcnt(4)" ::: "memory");   // A(0),B(0) resident; A(1) in flight
    __builtin_amdgcn_s_barrier();
#pragma unroll
    for (int mf = 0; mf < 4; ++mf) aC[mf] = rdA(&L[0], mf, 0);
#pragma unroll
    for (int nf = 0; nf < 4; ++nf) bC[nf] = rdB(&L[49152], nf, 0);

    // 32 tiles = 5 x 6 (lcm of rings 3,2) + 2 tail; literal ring indices.
    for (int t = 0; t < 30; t += 6) {
        doTile(0, 1, 2, 0, t);
        doTile(1, 2, 0, 1, t + 1);
        doTile(2, 0, 1, 0, t + 2);
        doTile(0, 1, 2, 1, t + 3);
        doTile(1, 2, 0, 0, t + 4);
        doTile(2, 0, 1, 1, t + 5);
    }
    doTile(0, 1, 2, 0, 30);
    doTile(1, 2, 0, 1, 31);

    // epilogue: C/D layout col = lane&15, row = (lane>>4)*4 + reg
    const int colbase = bn * 256 + wn * 64;
    const int rowbase = bm * 256 + wm * 128;
    float bsv[4];
#pragma unroll
    for (int nf = 0; nf < 4; ++nf) bsv[nf] = bias[colbase + nf * 16 + lr];
    float* Cb = C + (size_t)rowbase * QN + colbase;
#pragma unroll
    for (int mf = 0; mf < 8; ++mf)
#pragma unroll
        for (int nf = 0; nf < 4; ++nf)
#pragma unroll
            for (int v = 0; v < 4; ++v)
                Cb[(size_t)(mf * 16 + lg * 4 + v) * QN + nf * 16 + lr] = acc[mf][nf][v] + bsv[nf];
}

// ---------------------------------------------------------------------------
extern "C" void kernel_launch(void* const* d_in, const int* in_sizes, int n_in,
                              void* d_out, int out_size, void* d_ws, size_t ws_size,
                              hipStream_t stream) {
    const float* x    = (const float*)d_in[0];
    const float* wr   = (const float*)d_in[1];
    const float* wi   = (const float*)d_in[2];
    const float* wj   = (const float*)d_in[3];
    const float* wk   = (const float*)d_in[4];
    const float* bias = (const float*)d_in[5];
    float* out = (float*)d_out;

    u16* xb = (u16*)d_ws;                                   // 64 MB
    u16* wb = (u16*)((char*)d_ws + (size_t)QM * QK * 2);    // 8 MB

    prep_kernel<<<8192, 256, 0, stream>>>(x, xb, wr, wi, wj, wk, wb);
    qgemm_kernel<<<512, 512, 0, stream>>>(xb, wb, bias, out);
}

// Round 13
// 153.898 us; speedup vs baseline: 1.1512x; 1.1512x over previous
//
#include <hip/hip_runtime.h>

// ---------------------------------------------------------------------------
// QuaternionLinear == one dense GEMM: out[M,N] = x[M,K] @ W_eff[N,K]^T + bias
//   M = 16384 (B*S), N = 2048 (OUT_F), K = 2048 (IN_F)
// Pipeline: prep (fp32->bf16 x + build W_eff) ; qgemm.
// R13 = R7 rings/sync (A 2-ring + B 3-ring 160KB, chunk-XOR swizzle, ONE
// end-of-tile lgkm(0)+vmcnt(4)+barrier, literal ring indices, XCD swizzle)
// with the tile body REORDERED for one-cluster operand lookahead:
//   readsC0 | stageA0 readsC1 MFMA0 | stageA1 readsC2 MFMA1 |
//   stageB0 readsC3 MFMA2 | stageB1 END-sync barrier readsC0'  MFMA3
// Mechanism (R5-R12 evidence): in-order issue means a wave stalled issuing
// an MFMA burst cannot issue the next cluster's ds_reads -> LDS pipe and
// MFMA pipe serialize (tile ~ 2560+2483 cyc = measured 4650). Issuing each
// cluster's reads BEFORE the previous burst (and c0's after the barrier,
// covered by MFMA3) overlaps them. No fences; compiler keeps counted lgkm.
// R12 lesson: do NOT shorten B prefetch distance (B 3-ring stays).
// R9 lesson: no divergence around acc. R11 lesson: 16x16 frag pattern only.
// ---------------------------------------------------------------------------

typedef unsigned short u16;
typedef __bf16 bf16x8 __attribute__((ext_vector_type(8)));
typedef float f32x4 __attribute__((ext_vector_type(4)));

#define QM 16384
#define QN 2048
#define QK 2048

__device__ __forceinline__ u16 f2bf(float f) {
    union { float f; unsigned u; } v;
    v.f = f;
    unsigned r = v.u + 0x7FFFu + ((v.u >> 16) & 1u);
    return (u16)(r >> 16);
}

__device__ __forceinline__ void async_copy16(const u16* g, u16* l) {
    __builtin_amdgcn_global_load_lds(
        (const __attribute__((address_space(1))) void*)g,
        (__attribute__((address_space(3))) void*)l,
        16, 0, 0);
}

// ---------------------------------------------------------------------------
// prep: blocks [0,4096) convert x fp32->bf16; blocks [4096,8192) build W_eff.
// ---------------------------------------------------------------------------
__global__ void prep_kernel(const float* __restrict__ x, u16* __restrict__ xb,
                            const float* __restrict__ wr, const float* __restrict__ wi,
                            const float* __restrict__ wj, const float* __restrict__ wk,
                            u16* __restrict__ wb) {
    const int b = blockIdx.x;
    if (b < 4096) {
        const int n4 = (QM * QK) / 4;
        for (int i = b * blockDim.x + threadIdx.x; i < n4; i += 4096 * blockDim.x) {
            float4 v = reinterpret_cast<const float4*>(x)[i];
            ushort4 o;
            o.x = f2bf(v.x); o.y = f2bf(v.y); o.z = f2bf(v.z); o.w = f2bf(v.w);
            reinterpret_cast<ushort4*>(xb)[i] = o;
        }
    } else {
        int i = (b - 4096) * blockDim.x + threadIdx.x;   // [0, QN*QK/4)
        int n = i >> 9;
        int p = i & 511;
        int q = n >> 2, co = n & 3;
        int base = (q << 9) + p;
        float r  = wr[base], ii = wi[base], jj = wj[base], kk = wk[base];
        float e0, e1, e2, e3;
        if      (co == 0) { e0 = r;  e1 = -ii; e2 = -jj; e3 = -kk; }
        else if (co == 1) { e0 = ii; e1 = r;   e2 = -jj; e3 = kk;  }
        else if (co == 2) { e0 = jj; e1 = ii;  e2 = r;   e3 = -kk; }
        else              { e0 = kk; e1 = -ii; e2 = jj;  e3 = r;   }
        ushort4 o;
        o.x = f2bf(e0); o.y = f2bf(e1); o.z = f2bf(e2); o.w = f2bf(e3);
        reinterpret_cast<ushort4*>(wb)[(n << 9) + p] = o;
    }
}

// ---------------------------------------------------------------------------
// LDS (u16): A bufs [0,32768) = 2 x 16384; B bufs [32768,81920) = 3 x 16384.
// Buf = 256 rows x 64 cols; physical 16B-chunk (r,cp) holds logical
// (r, cp ^ (r&7)) [involution, verified 0-conflict 16x16 read pattern].
// Per K-tile t: read A-buf t&1, B-buf t%3; stage A(t+1)->(t+1)&1 (pos 0/1),
// B(t+2)->(t+2)%3 (pos 2/3). END sync: lgkm(0)+vmcnt(4)+barrier.
// Race proof (= R7, plus post-barrier pre-read):
//   [1] A(t+1) dest buf^1: tile-(t-1) readers drained at t-1's END lgkm(0);
//       residency for t+1 via END vmcnt(4).
//   [2] B(t+2) dest (t+2)%3 disjoint from read buf t%3 and (t+1)%3;
//       buf t%3 next written at t+1 (B(t+3)), after my reads drained.
//   [3] END queue = [B(t+1)x4, A(t+1)x4, B(t+2)x4]; vmcnt(4) => tile t+1
//       fully resident, B(t+2) stays in flight.
//   [4] post-barrier readsC0(t+1): A-buf (t+1)&1 resident per [3]+barrier;
//       B-buf (t+1)%3 resident since t-1; their next writers execute after
//       t+1's END barrier, my reads drain at t+1's END lgkm(0).
// ---------------------------------------------------------------------------
__global__ __launch_bounds__(512, 2) void qgemm_kernel(const u16* __restrict__ A,
                                                       const u16* __restrict__ B,
                                                       const float* __restrict__ bias,
                                                       float* __restrict__ C) {
    __shared__ __align__(16) u16 L[81920];      // 160 KB

    const int bid = blockIdx.x;                 // 512 blocks, %8==0
    const int swz = (bid & 7) * 64 + (bid >> 3);
    const int bm = swz >> 3;                    // 0..63
    const int bn = swz & 7;                     // 0..7

    const int tid = threadIdx.x;
    const int wid = tid >> 6, lane = tid & 63;
    const int wm = wid >> 2, wn = wid & 3;
    const int lr = lane & 15, lg = lane >> 4;

    const u16* Asrc = A + (size_t)bm * 256 * QK;
    const u16* Bsrc = B + (size_t)bn * 256 * QK;

    // staging: half-tile = 128 rows x 64 cols; thread covers rows {rA, rA+64}
    const int rA  = tid >> 3;                        // 0..63
    const int clA = ((tid & 7) ^ (rA & 7)) << 3;     // pre-swizzled global col
    const size_t soff = (size_t)rA * QK + clA;

    f32x4 acc[8][4];
#pragma unroll
    for (int i = 0; i < 8; ++i)
#pragma unroll
        for (int j = 0; j < 4; ++j)
            acc[i][j] = (f32x4){0.f, 0.f, 0.f, 0.f};

    auto stage = [&](const u16* src, int lbase, int k0) {
#pragma unroll
        for (int o = 0; o < 2; ++o)
            async_copy16(src + (size_t)(o * 64) * QK + k0 + soff,
                         &L[lbase + o * 4096 + wid * 512]);
    };

    auto rdA = [&](const u16* LA, int mf, int ks) -> bf16x8 {
        const int r = wm * 128 + mf * 16 + lr;
        const int c = ((ks * 4 + lg) ^ (r & 7)) << 3;
        return *(const bf16x8*)&LA[r * 64 + c];
    };
    auto rdB = [&](const u16* LB, int nf, int ks) -> bf16x8 {
        const int r = wn * 64 + nf * 16 + lr;
        const int c = ((ks * 4 + lg) ^ (r & 7)) << 3;
        return *(const bf16x8*)&LB[r * 64 + c];
    };

    // carried across the loop: current tile's c0 operands (read after the
    // previous tile's END barrier).
    bf16x8 a0[4], b0[4];

    // ab=t&1, bt=t%3, bt2=(t+2)%3, abn=(t+1)&1, btn=(t+1)%3 — all LITERAL.
    auto doTile = [&](const int ab, const int bt, const int bt2,
                      const int abn, const int btn, const int t,
                      const bool preRead) __attribute__((always_inline)) {
        const u16* LA  = &L[ab * 16384];
        const u16* LB  = &L[32768 + bt * 16384];
        const u16* LAn = &L[abn * 16384];
        const u16* LBn = &L[32768 + btn * 16384];
        const int tw1 = (t + 1) & 31, tw2 = (t + 2) & 31;
        const int oA = abn * 16384;               // A(t+1) dest
        const int oB = 32768 + bt2 * 16384;       // B(t+2) dest

        bf16x8 a1[4], b1[4], a2[4], a3[4];

        // ---- stage A(t+1)h0; readsC1; MFMA c0 (a0,b0 carried) ------------
        stage(Asrc, oA, tw1 * 64);
#pragma unroll
        for (int mf = 0; mf < 4; ++mf) a1[mf] = rdA(LA, 4 + mf, 0);
#pragma unroll
        for (int mf = 0; mf < 4; ++mf)
#pragma unroll
            for (int nf = 0; nf < 4; ++nf)
                acc[mf][nf] = __builtin_amdgcn_mfma_f32_16x16x32_bf16(a0[mf], b0[nf], acc[mf][nf], 0, 0, 0);

        // ---- stage A(t+1)h1; readsC2; MFMA c1 -----------------------------
        stage(Asrc + 128 * QK, oA + 8192, tw1 * 64);
#pragma unroll
        for (int nf = 0; nf < 4; ++nf) b1[nf] = rdB(LB, nf, 1);
#pragma unroll
        for (int mf = 0; mf < 4; ++mf) a2[mf] = rdA(LA, mf, 1);
#pragma unroll
        for (int mf = 0; mf < 4; ++mf)
#pragma unroll
            for (int nf = 0; nf < 4; ++nf)
                acc[4 + mf][nf] = __builtin_amdgcn_mfma_f32_16x16x32_bf16(a1[mf], b0[nf], acc[4 + mf][nf], 0, 0, 0);

        // ---- stage B(t+2)h0; readsC3; MFMA c2 -----------------------------
        stage(Bsrc, oB, tw2 * 64);
#pragma unroll
        for (int mf = 0; mf < 4; ++mf) a3[mf] = rdA(LA, 4 + mf, 1);
#pragma unroll
        for (int mf = 0; mf < 4; ++mf)
#pragma unroll
            for (int nf = 0; nf < 4; ++nf)
                acc[mf][nf] = __builtin_amdgcn_mfma_f32_16x16x32_bf16(a2[mf], b1[nf], acc[mf][nf], 0, 0, 0);

        // ---- stage B(t+2)h1; END sync; readsC0(t+1); MFMA c3 --------------
        stage(Bsrc + 128 * QK, oB + 8192, tw2 * 64);
        asm volatile("s_waitcnt lgkmcnt(0) vmcnt(4)" ::: "memory");
        __builtin_amdgcn_s_barrier();
        if (preRead) {
#pragma unroll
            for (int nf = 0; nf < 4; ++nf) b0[nf] = rdB(LBn, nf, 0);
#pragma unroll
            for (int mf = 0; mf < 4; ++mf) a0[mf] = rdA(LAn, mf, 0);
        }
#pragma unroll
        for (int mf = 0; mf < 4; ++mf)
#pragma unroll
            for (int nf = 0; nf < 4; ++nf)
                acc[4 + mf][nf] = __builtin_amdgcn_mfma_f32_16x16x32_bf16(a3[mf], b1[nf], acc[4 + mf][nf], 0, 0, 0);
    };

    // prologue: A(0)->Abuf0, B(0)->Bbuf0, B(1)->Bbuf1
    stage(Asrc,            0,             0);
    stage(Asrc + 128 * QK, 8192,          0);
    stage(Bsrc,            32768,             0);
    stage(Bsrc + 128 * QK, 32768 + 8192,      0);
    stage(Bsrc,            32768 + 16384,        64);
    stage(Bsrc + 128 * QK, 32768 + 16384 + 8192, 64);
    asm volatile("s_waitcnt vmcnt(4)" ::: "memory");   // A(0),B(0) resident
    __builtin_amdgcn_s_barrier();
    // read tile 0's c0 operands
#pragma unroll
    for (int nf = 0; nf < 4; ++nf) b0[nf] = rdB(&L[32768], nf, 0);
#pragma unroll
    for (int mf = 0; mf < 4; ++mf) a0[mf] = rdA(&L[0], mf, 0);

    // 32 tiles = 5 x 6 (lcm of rings 2,3) + 2 tail; literal ring indices.
    //            ab bt bt2 abn btn  t
    for (int t = 0; t < 30; t += 6) {
        doTile(0, 0, 2, 1, 1, t,     true);
        doTile(1, 1, 0, 0, 2, t + 1, true);
        doTile(0, 2, 1, 1, 0, t + 2, true);
        doTile(1, 0, 2, 0, 1, t + 3, true);
        doTile(0, 1, 0, 1, 2, t + 4, true);
        doTile(1, 2, 1, 0, 0, t + 5, true);
    }
    doTile(0, 0, 2, 1, 1, 30, true);
    doTile(1, 1, 0, 0, 2, 31, false);   // last tile: no wrap pre-read

    // epilogue: C/D layout col = lane&15, row = (lane>>4)*4 + reg
    const int colbase = bn * 256 + wn * 64;
    const int rowbase = bm * 256 + wm * 128;
    float bsv[4];
#pragma unroll
    for (int nf = 0; nf < 4; ++nf) bsv[nf] = bias[colbase + nf * 16 + lr];
    float* Cb = C + (size_t)rowbase * QN + colbase;
#pragma unroll
    for (int mf = 0; mf < 8; ++mf)
#pragma unroll
        for (int nf = 0; nf < 4; ++nf)
#pragma unroll
            for (int v = 0; v < 4; ++v)
                Cb[(size_t)(mf * 16 + lg * 4 + v) * QN + nf * 16 + lr] = acc[mf][nf][v] + bsv[nf];
}

// ---------------------------------------------------------------------------
extern "C" void kernel_launch(void* const* d_in, const int* in_sizes, int n_in,
                              void* d_out, int out_size, void* d_ws, size_t ws_size,
                              hipStream_t stream) {
    const float* x    = (const float*)d_in[0];
    const float* wr   = (const float*)d_in[1];
    const float* wi   = (const float*)d_in[2];
    const float* wj   = (const float*)d_in[3];
    const float* wk   = (const float*)d_in[4];
    const float* bias = (const float*)d_in[5];
    float* out = (float*)d_out;

    u16* xb = (u16*)d_ws;                                   // 64 MB
    u16* wb = (u16*)((char*)d_ws + (size_t)QM * QK * 2);    // 8 MB

    prep_kernel<<<8192, 256, 0, stream>>>(x, xb, wr, wi, wj, wk, wb);
    qgemm_kernel<<<512, 512, 0, stream>>>(xb, wb, bias, out);
}